// Round 16
// baseline (223.146 us; speedup 1.0000x reference)
//
#include <hip/hip_runtime.h>

typedef __attribute__((ext_vector_type(8))) short short8;
typedef __attribute__((ext_vector_type(4))) short short4v;
typedef __attribute__((ext_vector_type(4))) float float4v;

#define NPIX_HID 8388608   // 8*64*128*128
#define PST 132            // shorts per px row in LDS (pitch 66 dwords: measured 0 conflicts w/ b64)

__device__ __forceinline__ short f2bf(float f) {
    union { float f; unsigned u; } v; v.f = f;
    unsigned r = (v.u + 0x7FFFu + ((v.u >> 16) & 1u)) >> 16;
    return (short)r;
}

__device__ __forceinline__ float sigmoidf_(float v) { return 1.f / (1.f + __expf(-v)); }
__device__ __forceinline__ float tanhf_(float v)    { return 2.f / (1.f + __expf(-2.f * v)) - 1.f; }

// Pack W[co][ci][ky][kx] fp32 -> Aprep[kk][ci/8][co][ci%8] bf16 (MFMA A-frag order).
__global__ void wprep(const float* __restrict__ W, short* __restrict__ A) {
    int tid = blockIdx.x * 256 + threadIdx.x;
    if (tid >= 9 * 16 * 256 * 8) return;
    int j   = tid & 7;
    int co  = (tid >> 3) & 255;
    int cig = (tid >> 11) & 15;
    int kk  = tid >> 15;
    int ci  = cig * 8 + j;
    A[tid] = f2bf(W[co * 1152 + ci * 9 + kk]);
}

// One-time pre-pass: x,ph fp32 [b][c][y][x] -> H bf16 [b][y][x][ci 0..127]
// (ci<64 = x channels, ci>=64 = ph). LDS transpose keeps both sides coalesced.
__global__ __launch_bounds__(256) void xprep(const float* __restrict__ x,
                                             const float* __restrict__ ph,
                                             short* __restrict__ H) {
    __shared__ short Ht[64 * 132];     // [px 0..63][ci 0..127], pitch 132
    const int tid = threadIdx.x;
    const int t   = blockIdx.x;        // 2048: xh(2) x y(128) x b(8)
    const int xh  = t & 1;
    const int y   = (t >> 1) & 127;
    const int b   = t >> 8;
    const int xi  = tid & 63;          // x within half-row
    const int cq  = tid >> 6;          // 4 ci per iteration
    const int xbase = xh * 64;

#pragma unroll 8
    for (int it = 0; it < 32; ++it) {
        const int c = it * 4 + cq;
        const float* src = (c < 64)
            ? (x  + (((b * 64 + c)       * 128 + y) * 128 + xbase + xi))
            : (ph + (((b * 64 + (c & 63)) * 128 + y) * 128 + xbase + xi));
        Ht[xi * 132 + c] = f2bf(*src);
    }
    __syncthreads();

    short* Hb = H + (((b * 128 + y) * 128 + xbase) * 128);
#pragma unroll
    for (int r = 0; r < 4; ++r) {
        const int idx = r * 256 + tid;
        const int px  = idx >> 4;
        const int ch  = idx & 15;
        const short* sp = &Ht[px * 132 + ch * 8];
        short4v lo = *(const short4v*)sp;
        short4v hi = *(const short4v*)(sp + 4);
        *(short8*)(Hb + idx * 8) =
            __builtin_shufflevector(lo, hi, 0, 1, 2, 3, 4, 5, 6, 7);
    }
}

// Staging from H: one coalesced 16-B load + two b64 LDS writes per item.
// item i: oct = i&15 (ci chunk), px = (i>>4)%66, row = (i>>4)/66.
#define XL_LOAD(P, II)                                                        \
  {                                                                           \
    const int i_ = (II);                                                      \
    P##_act = (i_ < 4224);                                                    \
    const int pr_ = i_ >> 4;                                                  \
    P##_oct = i_ & 15;                                                        \
    P##_px  = pr_ % 66;                                                       \
    P##_row = pr_ / 66;                                                       \
    const int ys_ = y0 + P##_row - 1;                                         \
    const int xs_ = x0 + P##_px - 1;                                          \
    P##_ok = P##_act & ((unsigned)ys_ < 128u) & ((unsigned)xs_ < 128u);       \
    const short* hp_ = hsrc + (P##_ok ?                                       \
        ((((b * 128 + ys_) * 128 + xs_) * 128) + P##_oct * 8) : 0);           \
    P##_v = *(const short8*)hp_;                                              \
  }

#define XL_PROC(P)                                                            \
  if (P##_act) {                                                              \
    short8 v_ = P##_v;                                                        \
    if (!P##_ok) v_ = (short8){0, 0, 0, 0, 0, 0, 0, 0};                       \
    short* dst_ = &Bs[(P##_row * 66 + P##_px) * PST + P##_oct * 8];           \
    *(short4v*)dst_       = __builtin_shufflevector(v_, v_, 0, 1, 2, 3);      \
    *(short4v*)(dst_ + 4) = __builtin_shufflevector(v_, v_, 4, 5, 6, 7);      \
  }

// R10 structure (best: 2-row tile, 16x16x32 K-loop w/ 1-ahead A+B dbuf, setprio,
// XCD swizzle) + bf16-prepped staging (xprep): 1 load + 2 ds_writes per item,
// zero f2bf in the hot kernel.
__global__ __launch_bounds__(256, 2) void convlstm_main(
    const short* __restrict__ hsrc, const float* __restrict__ pc,
    const short* __restrict__ aprep, const float* __restrict__ bg,
    float* __restrict__ out)
{
    // Bs[halo row 0..3][px 0..65][ci 0..127], px pitch PST shorts -> 69696 B, 2 blocks/CU
    __shared__ short Bs[4 * 66 * PST];

    const int tid  = threadIdx.x;
    const int lane = tid & 63;
    const int wave = tid >> 6;
    const int l15  = lane & 15;
    const int quad = lane >> 4;

    // XCD-aware swizzle (verified: FETCH 119->55 MB).
    const int t  = (blockIdx.x & 7) * 128 + (blockIdx.x >> 3);
    const int x0 = (t & 1) * 64;
    const int y0 = ((t >> 1) & 63) * 2;
    const int b  = t >> 7;

    // ---- stage 4 halo rows x 66 px x 128 ci from H; 2-deep rotated pipeline ----
    {
        short8 stA_v; int stA_px, stA_row, stA_oct; bool stA_ok, stA_act;
        short8 stB_v; int stB_px, stB_row, stB_oct; bool stB_ok, stB_act;
        int ib = tid;
        XL_LOAD(stA, ib);
#pragma unroll 1
        for (int it = 0; it < 16; it += 2) {
            XL_LOAD(stB, ib + 256);
            XL_PROC(stA);
            XL_LOAD(stA, ib + 512);
            XL_PROC(stB);
            ib += 512;
        }
        XL_PROC(stA);                   // tail round 17 (act-guarded)
    }
    __syncthreads();

    float4v acc[4][8];
#pragma unroll
    for (int mt = 0; mt < 4; ++mt)
#pragma unroll
        for (int nt = 0; nt < 8; ++nt)
            acc[mt][nt] = (float4v){0.f, 0.f, 0.f, 0.f};

    // ---- K-loop: (ky,kx) unroll-1; kc unrolled; A AND B double-buffered one
    //      kc-step ahead (B prefetch crosses kx/ky boundaries) ----
    const short* ap = aprep + quad * 2048 + (wave * 16 + l15) * 8;   // + step*8192 + mt*512
    short8 abuf[2][4];
#pragma unroll
    for (int mt = 0; mt < 4; ++mt) abuf[0][mt] = *(const short8*)(ap + mt * 512);

    const short* bb = &Bs[l15 * PST + quad * 8];
    short8 bfr[2][8];
#pragma unroll
    for (int nt = 0; nt < 8; ++nt) {
        const short* bp = bb + (nt >> 2) * (66 * PST) + (nt & 3) * (16 * PST);
        short4v lo = *(const short4v*)bp;
        short4v hi = *(const short4v*)(bp + 4);
        bfr[0][nt] = __builtin_shufflevector(lo, hi, 0, 1, 2, 3, 4, 5, 6, 7);
    }

#pragma unroll 1
    for (int ky = 0; ky < 3; ++ky) {
#pragma unroll 1
        for (int kx = 0; kx < 3; ++kx) {
            const bool lastkx = (ky == 2) & (kx == 2);
            // kx+1: px window shifts 1; after kx=2: -2 px + 1 halo row = +64*PST
            const short* bbn = bb + ((kx == 2) ? 64 * PST : PST);
#pragma unroll
            for (int kc = 0; kc < 4; ++kc) {
                const int cur = kc & 1, nxt = cur ^ 1;
                const bool last = lastkx & (kc == 3);

                // A prefetch for next kc-step (reload current on very last step)
                const short* apn = last ? ap : (ap + 8192);
#pragma unroll
                for (int mt = 0; mt < 4; ++mt)
                    abuf[nxt][mt] = *(const short8*)(apn + mt * 512);
                ap = apn;

                // B prefetch for next kc-step (cross kx/ky boundary via bbn)
                const short* bq = (kc == 3) ? (lastkx ? bb : bbn) : bb;
                const int kcn = (kc + 1) & 3;
#pragma unroll
                for (int nt = 0; nt < 8; ++nt) {
                    const short* bp = bq + (nt >> 2) * (66 * PST) + (nt & 3) * (16 * PST) + kcn * 32;
                    short4v lo = *(const short4v*)bp;
                    short4v hi = *(const short4v*)(bp + 4);
                    bfr[nxt][nt] = __builtin_shufflevector(lo, hi, 0, 1, 2, 3, 4, 5, 6, 7);
                }

                // MFMA on current buffers (no in-loop barriers -> phase diversity;
                // setprio keeps the matrix pipe fed)
                __builtin_amdgcn_s_setprio(1);
#pragma unroll
                for (int mt = 0; mt < 4; ++mt)
#pragma unroll
                    for (int nt = 0; nt < 8; ++nt)
                        acc[mt][nt] = __builtin_amdgcn_mfma_f32_16x16x32_bf16(
                            abuf[cur][mt], bfr[cur][nt], acc[mt][nt], 0, 0, 0);
                __builtin_amdgcn_s_setprio(0);
            }
            bb = bbn;
        }
    }

    // ---- fused gating epilogue; pc loads hoisted ahead of all gating math ----
    float pcv[8][4];
#pragma unroll
    for (int nt = 0; nt < 8; ++nt) {
        const int y  = y0 + (nt >> 2);
        const int px = x0 + ((nt & 3) << 4) + l15;
#pragma unroll
        for (int r = 0; r < 4; ++r) {
            const int c = wave * 16 + quad * 4 + r;
            pcv[nt][r] = pc[((b * 64 + c) * 128 + y) * 128 + px];
        }
    }
#pragma unroll
    for (int nt = 0; nt < 8; ++nt) {
        const int y  = y0 + (nt >> 2);
        const int px = x0 + ((nt & 3) << 4) + l15;
#pragma unroll
        for (int r = 0; r < 4; ++r) {
            const int c = wave * 16 + quad * 4 + r;
            const float gi = acc[0][nt][r] + bg[c];
            const float gf = acc[1][nt][r] + bg[64 + c];
            const float go = acc[2][nt][r] + bg[128 + c];
            const float gc = acc[3][nt][r] + bg[192 + c];
            const float ig = sigmoidf_(gi);
            const float fg = sigmoidf_(gf);
            const float og = sigmoidf_(go);
            const float cg = tanhf_(gc);
            const int idx = ((b * 64 + c) * 128 + y) * 128 + px;
            const float cell = ig * cg + fg * pcv[nt][r];
            const float hid  = og * tanhf_(cell);
            out[idx] = hid;
            out[NPIX_HID + idx] = cell;
        }
    }
}

extern "C" void kernel_launch(void* const* d_in, const int* in_sizes, int n_in,
                              void* d_out, int out_size, void* d_ws, size_t ws_size,
                              hipStream_t stream) {
    const float* x  = (const float*)d_in[0];
    const float* ph = (const float*)d_in[1];
    const float* pc = (const float*)d_in[2];
    const float* W  = (const float*)d_in[3];
    const float* bg = (const float*)d_in[4];
    float* out = (float*)d_out;
    short* aprep = (short*)d_ws;              // 589,824 B
    short* H     = (short*)d_ws + 294912;     // 8*128*128*128 bf16 = 33,554,432 B

    wprep<<<1152, 256, 0, stream>>>(W, aprep);
    xprep<<<2048, 256, 0, stream>>>(x, ph, H);
    convlstm_main<<<1024, 256, 0, stream>>>(H, pc, aprep, bg, out);
}